// Round 1
// baseline (3333.326 us; speedup 1.0000x reference)
//
#include <hip/hip_runtime.h>

// ---------------- problem constants ----------------
#define N_NODES 100000
#define N_EDGES 1600000
#define DN 128
#define DE 48
#define HDIM 256
#define IN1 176            // DN + DE
#define K1 352             // 2*IN1  (concat [h | h_neigh] for layer 1)
#define K2 512             // 2*HDIM (concat [h1 | h_neigh] for layer 2)
#define NPAD 100096        // 782 * 128 (GEMM row padding)

typedef __bf16 bf16;
typedef __bf16 bf16x8 __attribute__((ext_vector_type(8)));
typedef float  f32x4  __attribute__((ext_vector_type(4)));

// ---------------- workspace layout (bytes) ----------------
// [deg][R (acc_e/acc1/acc2 overlay)][hcat1][hcat2][Wt1][Wt2]
// acc2 (102.4MB) overlays R (70.4MB) + head of hcat1 (dead by then).
#define O_DEG 0UL
#define O_R   400128UL                            // N*4 -> 400000, aligned up
#define O_H1  (O_R  + 70400000UL)                 // R = max(acc_e 19.2MB, acc1 70.4MB)
#define O_H2  (O_H1 + (size_t)NPAD * K1 * 2)      // hcat1: NPAD x 352 bf16
#define O_W1  (O_H2 + (size_t)NPAD * K2 * 2)      // hcat2: NPAD x 512 bf16
#define O_W2  (O_W1 + (size_t)HDIM * K1 * 2)      // Wt1: 256 x 352 bf16
// end = O_W2 + 256*512*2  ~= 244 MB

// ---------------- weight prep: bf16, transposed to [n][k], self/neigh stacked in k ----------------
__global__ void k_prep_weights(const float* __restrict__ Ws1, const float* __restrict__ Wn1,
                               const float* __restrict__ Ws2, const float* __restrict__ Wn2,
                               bf16* __restrict__ Wt1, bf16* __restrict__ Wt2) {
    int tid = blockIdx.x * 256 + threadIdx.x;
    if (tid < HDIM * K1) {
        int n = tid / K1, k = tid - n * K1;
        float v = (k < IN1) ? Ws1[k * HDIM + n] : Wn1[(k - IN1) * HDIM + n];
        Wt1[n * K1 + k] = (bf16)v;
    } else {
        int t2 = tid - HDIM * K1;   // grid sized exactly: t2 < HDIM*K2
        int n = t2 / K2, k = t2 - n * K2;
        float v = (k < HDIM) ? Ws2[k * HDIM + n] : Wn2[(k - HDIM) * HDIM + n];
        Wt2[n * K2 + k] = (bf16)v;
    }
}

// ---------------- degree (shared by all three seg-means) ----------------
__global__ void k_degree(const int* __restrict__ dst, float* __restrict__ deg) {
    int e = blockIdx.x * 256 + threadIdx.x;
    if (e < N_EDGES) unsafeAtomicAdd(&deg[dst[e]], 1.0f);
}

// ---------------- scatter edge features: acc_e[dst] += fe[e] ----------------
__global__ void k_scatter_edges(const float* __restrict__ fe, const int* __restrict__ dst,
                                float* __restrict__ acc) {
    int tid = blockIdx.x * 256 + threadIdx.x;   // E*48 = 76.8M, exact grid
    int e = tid / DE, j = tid - e * DE;
    unsafeAtomicAdd(&acc[dst[e] * DE + j], fe[tid]);
}

// ---------------- build hcat1 cols 0:176 = [node_feats | acc_e/deg] (bf16) ----------------
__global__ void k_build_h(const float* __restrict__ fn, const float* __restrict__ acc_e,
                          const float* __restrict__ deg, bf16* __restrict__ h) {
    int tid = blockIdx.x * 256 + threadIdx.x;   // N*176, exact grid
    int n = tid / IN1, j = tid - n * IN1;
    float v;
    if (j < DN) v = fn[n * DN + j];
    else        v = acc_e[n * DE + (j - DN)] / fmaxf(deg[n], 1.0f);
    h[(size_t)n * K1 + j] = (bf16)v;
}

// ---------------- scatter layer-1 neighbor sums: acc1[dst] += h[src, 0:176] ----------------
__global__ void k_scatter1(const bf16* __restrict__ h, const int* __restrict__ src,
                           const int* __restrict__ dst, float* __restrict__ acc) {
    int tid = blockIdx.x * 256 + threadIdx.x;   // E*176 = 281.6M, exact grid
    int e = tid / IN1, j = tid - e * IN1;
    float v = (float)h[(size_t)src[e] * K1 + j];
    unsafeAtomicAdd(&acc[dst[e] * IN1 + j], v);
}

// ---------------- hcat1 cols 176:352 = acc1/deg ----------------
__global__ void k_div1(const float* __restrict__ acc, const float* __restrict__ deg,
                       bf16* __restrict__ h) {
    int tid = blockIdx.x * 256 + threadIdx.x;   // N*176, exact grid
    int n = tid / IN1, j = tid - n * IN1;
    h[(size_t)n * K1 + IN1 + j] = (bf16)(acc[tid] / fmaxf(deg[n], 1.0f));
}

// ---------------- scatter layer-2: acc2[dst] += h2[src, 0:256] ----------------
__global__ void k_scatter2(const bf16* __restrict__ h2, const int* __restrict__ src,
                           const int* __restrict__ dst, float* __restrict__ acc) {
    unsigned tid = blockIdx.x * 256 + threadIdx.x;  // E*256 = 409.6M, exact grid
    int e = tid >> 8, j = tid & 255;
    float v = (float)h2[(size_t)src[e] * K2 + j];
    unsafeAtomicAdd(&acc[dst[e] * HDIM + j], v);
}

// ---------------- hcat2 cols 256:512 = acc2/deg ----------------
__global__ void k_div2(const float* __restrict__ acc, const float* __restrict__ deg,
                       bf16* __restrict__ h2) {
    int tid = blockIdx.x * 256 + threadIdx.x;   // N*256, exact grid
    int n = tid >> 8, j = tid & 255;
    h2[(size_t)n * K2 + HDIM + j] = (bf16)(acc[tid] / fmaxf(deg[n], 1.0f));
}

// ---------------- bf16 MFMA GEMM: C[NPAD,256] = A[NPAD,K] @ Wt^T + bias ----------------
// Block: 256 thr (4 waves), tile 128x128, BK=32. Wave = 64x64 (4x4 MFMA tiles).
// Wt stored [n][k] so B-frags are contiguous 8-bf16 reads.
// A-frag: A[m=lane&15][k=(lane>>4)*8+j]; B-frag: B[k][n=lane&15];
// D: col=lane&15, row=(lane>>4)*4+reg.
template <bool RELU, typename OT>
__global__ __launch_bounds__(256) void k_gemm(const bf16* __restrict__ A,
                                              const bf16* __restrict__ Wt,
                                              const float* __restrict__ bias,
                                              OT* __restrict__ out,
                                              int Ktiles, int ostride) {
    __shared__ __align__(16) bf16 lA[128 * 40];   // pad 32->40: 2-way bank alias only
    __shared__ __align__(16) bf16 lB[128 * 40];

    const int tid = threadIdx.x;
    const int rowBase = blockIdx.x * 128;
    const int colBase = blockIdx.y * 128;
    const int l = tid & 63, w = tid >> 6;
    const int wr = (w >> 1) * 64, wc = (w & 1) * 64;
    const int lm = l & 15, lq = l >> 4;
    const int K = Ktiles * 32;                    // == row stride of A and Wt

    const int srow = tid >> 1;                    // staging: 16 bf16 (32B) per thread
    const int sko  = (tid & 1) * 16;

    f32x4 acc[4][4] = {};

    for (int kt = 0; kt < Ktiles; ++kt) {
        const int k0 = kt * 32;
        const uint4* pa = (const uint4*)(A  + (size_t)(rowBase + srow) * K + k0 + sko);
        const uint4* pb = (const uint4*)(Wt + (size_t)(colBase + srow) * K + k0 + sko);
        uint4 a0 = pa[0], a1 = pa[1];
        uint4 b0 = pb[0], b1 = pb[1];
        __syncthreads();   // previous iteration's frag reads done before overwrite
        *(uint4*)&lA[srow * 40 + sko]     = a0;
        *(uint4*)&lA[srow * 40 + sko + 8] = a1;
        *(uint4*)&lB[srow * 40 + sko]     = b0;
        *(uint4*)&lB[srow * 40 + sko + 8] = b1;
        __syncthreads();

        bf16x8 af[4], bfr[4];
#pragma unroll
        for (int mi = 0; mi < 4; ++mi)
            af[mi] = *(const bf16x8*)&lA[(wr + mi * 16 + lm) * 40 + lq * 8];
#pragma unroll
        for (int ni = 0; ni < 4; ++ni)
            bfr[ni] = *(const bf16x8*)&lB[(wc + ni * 16 + lm) * 40 + lq * 8];
#pragma unroll
        for (int mi = 0; mi < 4; ++mi)
#pragma unroll
            for (int ni = 0; ni < 4; ++ni)
                acc[mi][ni] = __builtin_amdgcn_mfma_f32_16x16x32_bf16(
                    af[mi], bfr[ni], acc[mi][ni], 0, 0, 0);
    }

#pragma unroll
    for (int ni = 0; ni < 4; ++ni) {
        const int gcol = colBase + wc + ni * 16 + lm;
        const float bv = bias[gcol];
#pragma unroll
        for (int mi = 0; mi < 4; ++mi) {
#pragma unroll
            for (int r = 0; r < 4; ++r) {
                const int grow = rowBase + wr + mi * 16 + lq * 4 + r;
                if (grow < N_NODES) {
                    float v = acc[mi][ni][r] + bv;
                    if (RELU) v = fmaxf(v, 0.0f);
                    out[(size_t)grow * ostride + gcol] = (OT)v;
                }
            }
        }
    }
}

// ---------------- launcher ----------------
extern "C" void kernel_launch(void* const* d_in, const int* in_sizes, int n_in,
                              void* d_out, int out_size, void* d_ws, size_t ws_size,
                              hipStream_t stream) {
    const float* fn  = (const float*)d_in[0];
    const float* fe  = (const float*)d_in[1];
    const int*   src = (const int*)d_in[2];
    const int*   dst = (const int*)d_in[3];
    const float* Ws1 = (const float*)d_in[4];
    const float* Wn1 = (const float*)d_in[5];
    const float* b1  = (const float*)d_in[6];
    const float* Ws2 = (const float*)d_in[7];
    const float* Wn2 = (const float*)d_in[8];
    const float* b2  = (const float*)d_in[9];
    float* out = (float*)d_out;

    char* ws = (char*)d_ws;
    float* deg = (float*)(ws + O_DEG);
    float* R   = (float*)(ws + O_R);     // acc_e, then acc1, then acc2 (overlay)
    bf16*  h1  = (bf16*)(ws + O_H1);
    bf16*  h2  = (bf16*)(ws + O_H2);
    bf16*  Wt1 = (bf16*)(ws + O_W1);
    bf16*  Wt2 = (bf16*)(ws + O_W2);

    // zero: degree, edge accumulator, GEMM pad rows of hcat1/hcat2
    hipMemsetAsync(deg, 0, (size_t)N_NODES * 4, stream);
    hipMemsetAsync(R, 0, (size_t)N_NODES * DE * 4, stream);
    hipMemsetAsync((char*)h1 + (size_t)N_NODES * K1 * 2, 0, (size_t)(NPAD - N_NODES) * K1 * 2, stream);
    hipMemsetAsync((char*)h2 + (size_t)N_NODES * K2 * 2, 0, (size_t)(NPAD - N_NODES) * K2 * 2, stream);

    k_prep_weights<<<(HDIM * K1 + HDIM * K2) / 256, 256, 0, stream>>>(Ws1, Wn1, Ws2, Wn2, Wt1, Wt2);
    k_degree<<<(N_EDGES + 255) / 256, 256, 0, stream>>>(dst, deg);
    k_scatter_edges<<<N_EDGES * DE / 256, 256, 0, stream>>>(fe, dst, R);
    k_build_h<<<N_NODES * IN1 / 256, 256, 0, stream>>>(fn, R, deg, h1);

    hipMemsetAsync(R, 0, (size_t)N_NODES * IN1 * 4, stream);
    k_scatter1<<<N_EDGES * IN1 / 256, 256, 0, stream>>>(h1, src, dst, R);
    k_div1<<<N_NODES * IN1 / 256, 256, 0, stream>>>(R, deg, h1);
    k_gemm<true, bf16><<<dim3(NPAD / 128, 2), 256, 0, stream>>>(h1, Wt1, b1, h2, K1 / 32, K2);

    hipMemsetAsync(R, 0, (size_t)N_NODES * HDIM * 4, stream);
    k_scatter2<<<N_EDGES * HDIM / 256, 256, 0, stream>>>(h2, src, dst, R);
    k_div2<<<N_NODES * HDIM / 256, 256, 0, stream>>>(R, deg, h2);
    k_gemm<false, float><<<dim3(NPAD / 128, 2), 256, 0, stream>>>(h2, Wt2, b2, out, K2 / 32, HDIM);
}

// Round 2
// 1363.030 us; speedup vs baseline: 2.4455x; 2.4455x over previous
//
#include <hip/hip_runtime.h>

// ---------------- problem constants ----------------
#define N_NODES 100000
#define N_EDGES 1600000
#define DN 128
#define DE 48
#define HDIM 256
#define IN1 176            // DN + DE
#define K1 352             // 2*IN1  (concat [h | h_neigh] for layer 1)
#define K2 512             // 2*HDIM (concat [h1 | h_neigh] for layer 2)
#define NPAD 100096        // 782 * 128 (GEMM row padding; also 391*256 scan width)
#define NB 391             // scan blocks = NPAD/256

typedef __bf16 bf16;
typedef __bf16 bf16x2 __attribute__((ext_vector_type(2)));
typedef __bf16 bf16x8 __attribute__((ext_vector_type(8)));
typedef float  f32x4  __attribute__((ext_vector_type(4)));

// ---------------- workspace layout (bytes) ----------------
#define O_DEG  0UL                      // NPAD int
#define O_ROW  400384UL                 // NPAD int (rowptr)
#define O_CUR  800768UL                 // NPAD int (fill cursor)
#define O_PRE  1201152UL                // NPAD int (block-local prefix)
#define O_PART 1601536UL                // 512 int (block partials)
#define O_CSR  1603584UL                // E int2 (src, eid) = 12.8 MB
#define O_H1   14403584UL               // NPAD x 352 bf16 = 70.5 MB
#define O_H2   84871168UL               // NPAD x 512 bf16 = 102.5 MB
#define O_W1   187369472UL              // 256 x 352 bf16
#define O_W2   187549696UL              // 256 x 512 bf16; end ~188 MB

__device__ __forceinline__ float bf_lo(unsigned u) { return __uint_as_float(u << 16); }
__device__ __forceinline__ float bf_hi(unsigned u) { return __uint_as_float(u & 0xffff0000u); }
__device__ __forceinline__ unsigned bf_pk(float a, float b) {
    union { bf16x2 v; unsigned u; } t;
    t.v.x = (bf16)a; t.v.y = (bf16)b;
    return t.u;
}

// ---------------- weight prep: bf16, transposed to [n][k], self/neigh stacked in k ----------------
__global__ void k_prep_weights(const float* __restrict__ Ws1, const float* __restrict__ Wn1,
                               const float* __restrict__ Ws2, const float* __restrict__ Wn2,
                               bf16* __restrict__ Wt1, bf16* __restrict__ Wt2) {
    int tid = blockIdx.x * 256 + threadIdx.x;
    if (tid < HDIM * K1) {
        int n = tid / K1, k = tid - n * K1;
        float v = (k < IN1) ? Ws1[k * HDIM + n] : Wn1[(k - IN1) * HDIM + n];
        Wt1[n * K1 + k] = (bf16)v;
    } else {
        int t2 = tid - HDIM * K1;
        int n = t2 / K2, k = t2 - n * K2;
        float v = (k < HDIM) ? Ws2[k * HDIM + n] : Wn2[(k - HDIM) * HDIM + n];
        Wt2[n * K2 + k] = (bf16)v;
    }
}

// ---------------- CSR build ----------------
__global__ void k_count(const int* __restrict__ dst, int* __restrict__ deg) {
    int e = blockIdx.x * 256 + threadIdx.x;
    if (e < N_EDGES) atomicAdd(&deg[dst[e]], 1);
}

// block-inclusive Hillis-Steele scan over `lds`, returns inclusive prefix of v
template <int NT>
__device__ __forceinline__ int block_scan_inc(int v, int* lds) {
    int tid = threadIdx.x;
    lds[tid] = v;
#pragma unroll
    for (int off = 1; off < NT; off <<= 1) {
        __syncthreads();
        int t = (tid >= off) ? lds[tid - off] : 0;
        __syncthreads();
        lds[tid] += t;
    }
    return lds[tid];
}

__global__ void k_scanA(const int* __restrict__ deg, int* __restrict__ presum,
                        int* __restrict__ part) {
    __shared__ int lds[256];
    int idx = blockIdx.x * 256 + threadIdx.x;
    int v = (idx < N_NODES) ? deg[idx] : 0;
    int inc = block_scan_inc<256>(v, lds);
    presum[idx] = inc - v;
    if (threadIdx.x == 255) part[blockIdx.x] = inc;
}

__global__ void k_scanB(int* __restrict__ part) {
    __shared__ int lds[512];
    int t = threadIdx.x;
    int v = (t < NB) ? part[t] : 0;
    int inc = block_scan_inc<512>(v, lds);
    if (t < NB) part[t] = inc - v;   // exclusive
}

__global__ void k_scanC(const int* __restrict__ presum, const int* __restrict__ part,
                        int* __restrict__ rowptr, int* __restrict__ cursor) {
    int idx = blockIdx.x * 256 + threadIdx.x;
    int v = presum[idx] + part[blockIdx.x];
    if (idx < N_NODES) { rowptr[idx] = v; cursor[idx] = v; }
}

__global__ void k_fill(const int* __restrict__ src, const int* __restrict__ dst,
                       int* __restrict__ cursor, int2* __restrict__ csr) {
    int e = blockIdx.x * 256 + threadIdx.x;   // exact grid
    int p = atomicAdd(&cursor[dst[e]], 1);
    csr[p] = make_int2(src[e], e);
}

// ---------------- aggregation: one wave per node ----------------
// h1 row n, cols 0:128 = fn[n]; cols 128:176 = mean of fe over incoming edges
__global__ void k_agg_edges(const float* __restrict__ fn, const float* __restrict__ fe,
                            const int* __restrict__ rowptr, const int* __restrict__ deg,
                            const int2* __restrict__ csr, bf16* __restrict__ h1) {
    int node = blockIdx.x * 4 + (threadIdx.x >> 6);  // grid 25000 exact
    int lane = threadIdx.x & 63;
    bf16* row = h1 + (size_t)node * K1;
    float2 f = *(const float2*)(fn + (size_t)node * DN + lane * 2);
    *(unsigned*)&row[lane * 2] = bf_pk(f.x, f.y);
    int base = rowptr[node], d = deg[node];
    float s = 0.f;
    for (int i = 0; i < d; ++i) {
        int eid = csr[base + i].y;
        if (lane < DE) s += fe[(size_t)eid * DE + lane];
    }
    float r = 1.0f / (float)max(d, 1);
    if (lane < DE) row[DN + lane] = (bf16)(s * r);
}

// h1 cols 176:352 = mean over incoming edges of h1[src, 0:176]
__global__ void k_agg1(const int* __restrict__ rowptr, const int* __restrict__ deg,
                       const int2* __restrict__ csr, bf16* __restrict__ h1) {
    int node = blockIdx.x * 4 + (threadIdx.x >> 6);
    int lane = threadIdx.x & 63;
    int base = rowptr[node], d = deg[node];
    float s0 = 0.f, s1 = 0.f, s2 = 0.f, s3 = 0.f;
    for (int i = 0; i < d; ++i) {
        int sv = csr[base + i].x;
        const unsigned* r32 = (const unsigned*)(h1 + (size_t)sv * K1);
        unsigned u0 = r32[lane];
        s0 += bf_lo(u0); s1 += bf_hi(u0);
        if (lane < 24) {
            unsigned u1 = r32[64 + lane];
            s2 += bf_lo(u1); s3 += bf_hi(u1);
        }
    }
    float r = 1.0f / (float)max(d, 1);
    unsigned* o32 = (unsigned*)(h1 + (size_t)node * K1 + IN1);
    o32[lane] = bf_pk(s0 * r, s1 * r);
    if (lane < 24) o32[64 + lane] = bf_pk(s2 * r, s3 * r);
}

// h2 cols 256:512 = mean over incoming edges of h2[src, 0:256]
__global__ void k_agg2(const int* __restrict__ rowptr, const int* __restrict__ deg,
                       const int2* __restrict__ csr, bf16* __restrict__ h2) {
    int node = blockIdx.x * 4 + (threadIdx.x >> 6);
    int lane = threadIdx.x & 63;
    int base = rowptr[node], d = deg[node];
    float s0 = 0.f, s1 = 0.f, s2 = 0.f, s3 = 0.f;
    for (int i = 0; i < d; ++i) {
        int sv = csr[base + i].x;
        uint2 u = ((const uint2*)(h2 + (size_t)sv * K2))[lane];
        s0 += bf_lo(u.x); s1 += bf_hi(u.x);
        s2 += bf_lo(u.y); s3 += bf_hi(u.y);
    }
    float r = 1.0f / (float)max(d, 1);
    uint2 o;
    o.x = bf_pk(s0 * r, s1 * r);
    o.y = bf_pk(s2 * r, s3 * r);
    ((uint2*)(h2 + (size_t)node * K2 + HDIM))[lane] = o;
}

// ---------------- bf16 MFMA GEMM: C[NPAD,256] = A[NPAD,K] @ Wt^T + bias ----------------
template <bool RELU, typename OT>
__global__ __launch_bounds__(256) void k_gemm(const bf16* __restrict__ A,
                                              const bf16* __restrict__ Wt,
                                              const float* __restrict__ bias,
                                              OT* __restrict__ out,
                                              int Ktiles, int ostride) {
    __shared__ __align__(16) bf16 lA[128 * 40];
    __shared__ __align__(16) bf16 lB[128 * 40];

    const int tid = threadIdx.x;
    const int rowBase = blockIdx.x * 128;
    const int colBase = blockIdx.y * 128;
    const int l = tid & 63, w = tid >> 6;
    const int wr = (w >> 1) * 64, wc = (w & 1) * 64;
    const int lm = l & 15, lq = l >> 4;
    const int K = Ktiles * 32;

    const int srow = tid >> 1;
    const int sko  = (tid & 1) * 16;

    f32x4 acc[4][4] = {};

    for (int kt = 0; kt < Ktiles; ++kt) {
        const int k0 = kt * 32;
        const uint4* pa = (const uint4*)(A  + (size_t)(rowBase + srow) * K + k0 + sko);
        const uint4* pb = (const uint4*)(Wt + (size_t)(colBase + srow) * K + k0 + sko);
        uint4 a0 = pa[0], a1 = pa[1];
        uint4 b0 = pb[0], b1 = pb[1];
        __syncthreads();
        *(uint4*)&lA[srow * 40 + sko]     = a0;
        *(uint4*)&lA[srow * 40 + sko + 8] = a1;
        *(uint4*)&lB[srow * 40 + sko]     = b0;
        *(uint4*)&lB[srow * 40 + sko + 8] = b1;
        __syncthreads();

        bf16x8 af[4], bfr[4];
#pragma unroll
        for (int mi = 0; mi < 4; ++mi)
            af[mi] = *(const bf16x8*)&lA[(wr + mi * 16 + lm) * 40 + lq * 8];
#pragma unroll
        for (int ni = 0; ni < 4; ++ni)
            bfr[ni] = *(const bf16x8*)&lB[(wc + ni * 16 + lm) * 40 + lq * 8];
#pragma unroll
        for (int mi = 0; mi < 4; ++mi)
#pragma unroll
            for (int ni = 0; ni < 4; ++ni)
                acc[mi][ni] = __builtin_amdgcn_mfma_f32_16x16x32_bf16(
                    af[mi], bfr[ni], acc[mi][ni], 0, 0, 0);
    }

#pragma unroll
    for (int ni = 0; ni < 4; ++ni) {
        const int gcol = colBase + wc + ni * 16 + lm;
        const float bv = bias[gcol];
#pragma unroll
        for (int mi = 0; mi < 4; ++mi) {
#pragma unroll
            for (int r = 0; r < 4; ++r) {
                const int grow = rowBase + wr + mi * 16 + lq * 4 + r;
                if (grow < N_NODES) {
                    float v = acc[mi][ni][r] + bv;
                    if (RELU) v = fmaxf(v, 0.0f);
                    out[(size_t)grow * ostride + gcol] = (OT)v;
                }
            }
        }
    }
}

// ---------------- launcher ----------------
extern "C" void kernel_launch(void* const* d_in, const int* in_sizes, int n_in,
                              void* d_out, int out_size, void* d_ws, size_t ws_size,
                              hipStream_t stream) {
    const float* fn  = (const float*)d_in[0];
    const float* fe  = (const float*)d_in[1];
    const int*   src = (const int*)d_in[2];
    const int*   dst = (const int*)d_in[3];
    const float* Ws1 = (const float*)d_in[4];
    const float* Wn1 = (const float*)d_in[5];
    const float* b1  = (const float*)d_in[6];
    const float* Ws2 = (const float*)d_in[7];
    const float* Wn2 = (const float*)d_in[8];
    const float* b2  = (const float*)d_in[9];
    float* out = (float*)d_out;

    char* ws = (char*)d_ws;
    int*  deg    = (int*)(ws + O_DEG);
    int*  rowptr = (int*)(ws + O_ROW);
    int*  cursor = (int*)(ws + O_CUR);
    int*  presum = (int*)(ws + O_PRE);
    int*  part   = (int*)(ws + O_PART);
    int2* csr    = (int2*)(ws + O_CSR);
    bf16* h1  = (bf16*)(ws + O_H1);
    bf16* h2  = (bf16*)(ws + O_H2);
    bf16* Wt1 = (bf16*)(ws + O_W1);
    bf16* Wt2 = (bf16*)(ws + O_W2);

    hipMemsetAsync(deg, 0, (size_t)NPAD * 4, stream);
    hipMemsetAsync((char*)h1 + (size_t)N_NODES * K1 * 2, 0, (size_t)(NPAD - N_NODES) * K1 * 2, stream);
    hipMemsetAsync((char*)h2 + (size_t)N_NODES * K2 * 2, 0, (size_t)(NPAD - N_NODES) * K2 * 2, stream);

    k_prep_weights<<<(HDIM * K1 + HDIM * K2) / 256, 256, 0, stream>>>(Ws1, Wn1, Ws2, Wn2, Wt1, Wt2);

    // CSR build
    k_count<<<(N_EDGES + 255) / 256, 256, 0, stream>>>(dst, deg);
    k_scanA<<<NB, 256, 0, stream>>>(deg, presum, part);
    k_scanB<<<1, 512, 0, stream>>>(part);
    k_scanC<<<NB, 256, 0, stream>>>(presum, part, rowptr, cursor);
    k_fill<<<N_EDGES / 256, 256, 0, stream>>>(src, dst, cursor, csr);

    // layer 1
    k_agg_edges<<<N_NODES / 4, 256, 0, stream>>>(fn, fe, rowptr, deg, csr, h1);
    k_agg1<<<N_NODES / 4, 256, 0, stream>>>(rowptr, deg, csr, h1);
    k_gemm<true, bf16><<<dim3(NPAD / 128, 2), 256, 0, stream>>>(h1, Wt1, b1, h2, K1 / 32, K2);

    // layer 2
    k_agg2<<<N_NODES / 4, 256, 0, stream>>>(rowptr, deg, csr, h2);
    k_gemm<false, float><<<dim3(NPAD / 128, 2), 256, 0, stream>>>(h2, Wt2, b2, out, K2 / 32, HDIM);
}